// Round 6
// baseline (1104.073 us; speedup 1.0000x reference)
//
#include <hip/hip_runtime.h>
#include <stdint.h>

// Problem dims
#define HDIM   1024
#define BDIM   128
#define TSTEPS 128
#define DDIM   256
#define ODIM   1024

// Workspace byte offsets
// flags: u32 flag[8][64] @ 0 (2048 B). grid counter cnt2[j] @ 2560 + j*128.
// All < 8192, zeroed by the memset.
#define WS_FLAG  0
#define WS_CNT2  2560
#define WS_HBUF  8192                                  // ushort [2][128][1024]
#define WS_HFIN  (WS_HBUF + 2*BDIM*HDIM*2)             // float  [128][1024]
#define WS_PBUF  (WS_HFIN + BDIM*HDIM*4)               // float  [128][1024]
#define WS_WHHI  (WS_PBUF + BDIM*ODIM*4)               // ushort [4096][1024]
#define WS_WHLO  (WS_WHHI + 4*HDIM*HDIM*2)             // ushort [4096][1024]
#define WS_WXHI  (WS_WHLO + 4*HDIM*HDIM*2)             // ushort [4096][256]
#define WS_XT    (WS_WXHI + 4*HDIM*DDIM*2)             // ushort [128][128][256]

// LDS: h-tile stage (16 rows) + K-partial reduction buffer.
// sH[16][HROW]: HROW=1032 shorts (pad 8 -> 4-bank row rotation; b128 A-frag reads
//   land 8 dwords/bank = conflict-free minimum).
// sG[4][16][SROW]: SROW=66 -> scatter banks (8*fg+fr)%32, max 2-way (free).
#define HROW 1032
#define SROW 66
#define SMEM_SH_BYTES (16*HROW*2)                       // 33,024
#define SMEM_BYTES    (SMEM_SH_BYTES + 4*16*SROW*4)     // 49,920

typedef __attribute__((ext_vector_type(8))) short frag8;
typedef __attribute__((ext_vector_type(4))) float f32x4;

__device__ __forceinline__ unsigned short f2bf(float f) {
  union { float f; unsigned u; } v; v.f = f;
  unsigned r = v.u + 0x7fffu + ((v.u >> 16) & 1u);   // RNE
  return (unsigned short)(r >> 16);
}
__device__ __forceinline__ float bf2f(unsigned short h) {
  union { unsigned u; float f; } v; v.u = ((unsigned)h) << 16;
  return v.f;
}
__device__ __forceinline__ float sigm(float x) { return 1.f / (1.f + __expf(-x)); }
__device__ __forceinline__ float tanh_f(float x) {
  x = fminf(fmaxf(x, -20.f), 20.f);
  float e = __expf(2.f * x);
  return (e - 1.f) / (e + 1.f);
}

// Coherence idiom (gfx950, non-coherent per-XCD L2) — R2/R5-validated:
//  - producers: relaxed AGENT atomic stores (write-through to LLC)
//  - release: __syncthreads() drains vmcnt(0) before the flag store
//  - consumers: wave-parallel relaxed poll of per-producer monotone flags
//    (lane l polls flag[l], __all ballot; plain stores, no RMW serialization),
//    then ONE fence(ACQUIRE,"agent"), then normal cached loads.
__device__ __forceinline__ void st_agent_u16(unsigned short* p, unsigned short v) {
  __hip_atomic_store(p, v, __ATOMIC_RELAXED, __HIP_MEMORY_SCOPE_AGENT);
}
__device__ __forceinline__ void st_agent_f32(float* p, float v) {
  __hip_atomic_store(p, v, __ATOMIC_RELAXED, __HIP_MEMORY_SCOPE_AGENT);
}
// Direct global->LDS DMA, 16B per lane (LDS dest wave-uniform; HW adds lane*16).
__device__ __forceinline__ void gload_lds16(const unsigned short* g, unsigned short* l) {
  __builtin_amdgcn_global_load_lds(
      (const __attribute__((address_space(1))) unsigned int*)(g),
      (__attribute__((address_space(3))) unsigned int*)(l),
      16, 0, 0);
}

// ---------------- prep: fp32 -> bf16 (hi/lo) reformat + x transpose (unchanged) ------------
__global__ void prep_kernel(const float* __restrict__ Wh, const float* __restrict__ Wx,
                            const float* __restrict__ x, unsigned char* __restrict__ ws)
{
  unsigned short* whhi = (unsigned short*)(ws + WS_WHHI);
  unsigned short* whlo = (unsigned short*)(ws + WS_WHLO);
  unsigned short* wxhi = (unsigned short*)(ws + WS_WXHI);
  unsigned short* xt   = (unsigned short*)(ws + WS_XT);
  const int NWH = 4*HDIM*HDIM/4;       // 1,048,576 float4 items
  const int NWX = 4*HDIM*DDIM/4;       //   262,144
  const int NX  = BDIM*TSTEPS*DDIM/4;  // 1,048,576
  int stride = gridDim.x * blockDim.x;
  for (int i = blockIdx.x*blockDim.x + threadIdx.x; i < NWH+NWX+NX; i += stride) {
    if (i < NWH) {
      float4 w = ((const float4*)Wh)[i];
      ushort4 hi, lo;
      hi.x = f2bf(w.x); lo.x = f2bf(w.x - bf2f(hi.x));
      hi.y = f2bf(w.y); lo.y = f2bf(w.y - bf2f(hi.y));
      hi.z = f2bf(w.z); lo.z = f2bf(w.z - bf2f(hi.z));
      hi.w = f2bf(w.w); lo.w = f2bf(w.w - bf2f(hi.w));
      ((ushort4*)whhi)[i] = hi;
      ((ushort4*)whlo)[i] = lo;
    } else if (i < NWH + NWX) {
      int j = i - NWH;
      float4 w = ((const float4*)Wx)[j];
      ushort4 hi;
      hi.x = f2bf(w.x); hi.y = f2bf(w.y); hi.z = f2bf(w.z); hi.w = f2bf(w.w);
      ((ushort4*)wxhi)[j] = hi;
    } else {
      int j = i - NWH - NWX;           // x flat [b][t][dv]
      int dv = j & 63;
      int t  = (j >> 6) & (TSTEPS - 1);
      int b  = j >> 13;
      float4 w = ((const float4*)x)[j];
      ushort4 hv;
      hv.x = f2bf(w.x); hv.y = f2bf(w.y); hv.z = f2bf(w.z); hv.w = f2bf(w.w);
      ((ushort4*)xt)[((size_t)t*BDIM + b)*64 + dv] = hv;   // xT[t][b][d]
    }
  }
}

// ---------------- persistent LSTM kernel (cooperative, 256 blocks x 512 thr) ----------------
// TWO-CHAIN INTERLEAVE: rows split into 8 independent groups x 16 rows. Block
// (mh = blockIdx&3, nsl = blockIdx>>2) owns h-cols [nsl*16,+16) and processes TWO tiles
// per round with the SAME weight registers (weights depend only on cols/gates/K-slice):
//   tile A = row-group mh   (rows [mh*16,+16))
//   tile B = row-group mh+4 (rows [64+mh*16,+16))
// Chain A's publish->wait latency hides under chain B's compute and vice versa.
// Barrier: per-producer flag array flag[8][64]; producers plain-store t+1 (after vmcnt
// drain); consumers poll wave-parallel (lane l of wave 0 polls flag l, __all ballot).
__global__ void __launch_bounds__(512, 2)
lstm_main(const float* __restrict__ bx, const float* __restrict__ Wp,
          const float* __restrict__ bp, unsigned char* __restrict__ ws,
          float* __restrict__ out)
{
  extern __shared__ unsigned char smem[];
  unsigned short* sH = (unsigned short*)smem;                          // [16][HROW]
  float (*sG)[16][SROW] = (float (*)[16][SROW])(smem + SMEM_SH_BYTES); // [4][16][SROW]

  unsigned short* hbuf = (unsigned short*)(ws + WS_HBUF);
  float*          hfin = (float*)(ws + WS_HFIN);
  float*          pbuf = (float*)(ws + WS_PBUF);
  const unsigned short* whhi = (const unsigned short*)(ws + WS_WHHI);
  const unsigned short* whlo = (const unsigned short*)(ws + WS_WHLO);
  const unsigned short* wxhi = (const unsigned short*)(ws + WS_WXHI);
  const unsigned short* xt   = (const unsigned short*)(ws + WS_XT);
  unsigned* flags = (unsigned*)(ws + WS_FLAG);
  unsigned* cnt2  = (unsigned*)(ws + WS_CNT2);

  const int tid  = threadIdx.x;
  const int lane = tid & 63;
  const int wv   = tid >> 6;      // wave 0..7
  const int wn   = wv >> 2;       // gate pair: gates {wn*2, wn*2+1}
  const int wk   = wv & 3;        // K quarter: H cols [wk*256,+256), D cols [wk*64,+64)
  const int fr   = lane & 15;     // MFMA frag row (m for A, n for B)
  const int fg   = lane >> 4;     // k-group 0..3
  const int mh   = blockIdx.x & 3;
  const int nsl  = blockIdx.x >> 2;    // 0..63
  const int hc0  = nsl << 4;           // 16 h-cols
  const int ga   = mh, gb = mh + 4;    // row-groups of this block's two chains
  const int a0   = mh << 4;            // A rows [a0,+16)
  const int b0   = 64 + (mh << 4);     // B rows [b0,+16)
  const int jln  = nsl & 3;

  // ---- preload this wave's weight fragments into registers (once, time-invariant) ----
  frag8 whi_[2][8], wlo_[2][8], wx_[2][2];
  #pragma unroll
  for (int nt = 0; nt < 2; ++nt) {
    const int g = wn*2 + nt;
    const size_t grow = (size_t)g*HDIM + hc0 + fr;
    const unsigned short* ph = whhi + grow*HDIM + wk*256 + fg*8;
    const unsigned short* pl = whlo + grow*HDIM + wk*256 + fg*8;
    #pragma unroll
    for (int kc = 0; kc < 8; ++kc) {
      whi_[nt][kc] = *(const frag8*)(ph + kc*32);
      wlo_[nt][kc] = *(const frag8*)(pl + kc*32);
    }
    const unsigned short* px = wxhi + grow*DDIM + wk*64 + fg*8;
    #pragma unroll
    for (int kc = 0; kc < 2; ++kc)
      wx_[nt][kc] = *(const frag8*)(px + kc*32);
  }
  #pragma unroll
  for (int nt = 0; nt < 2; ++nt) {
    #pragma unroll
    for (int kc = 0; kc < 8; ++kc)
      asm volatile("" : "+v"(whi_[nt][kc]), "+v"(wlo_[nt][kc]));
    #pragma unroll
    for (int kc = 0; kc < 2; ++kc)
      asm volatile("" : "+v"(wx_[nt][kc]));
  }

  // update-phase mapping: halves of the block own the two chains' cell states.
  // tid<256 -> chain A cell (row a0+um, col hc0+uj); tid>=256 -> chain B.
  const int uj = tid & 15;
  const int um = (tid >> 4) & 15;
  const float bg = bx[0*HDIM + hc0 + uj];
  const float bi = bx[1*HDIM + hc0 + uj];
  const float bf = bx[2*HDIM + hc0 + uj];
  const float bo = bx[3*HDIM + hc0 + uj];

  float cA = 0.f, cB = 0.f;

// One chain phase: x-path MFMA (pre-wait overlap), wave-parallel flag poll + fence,
// LDS stage, h-path MFMA, scatter, half-block reduce/update, publish flag.
#define PHASE(G, R0, HALF, CVAR)                                                       \
  {                                                                                    \
    f32x4 acc0 = {0.f,0.f,0.f,0.f}, acc1 = {0.f,0.f,0.f,0.f};                          \
    { /* x-path */                                                                     \
      const unsigned short* xb = xt + ((size_t)t*BDIM + (R0) + fr)*DDIM + wk*64 + fg*8;\
      _Pragma("unroll")                                                                \
      for (int kc = 0; kc < 2; ++kc) {                                                 \
        frag8 a = *(const frag8*)(xb + kc*32);                                         \
        acc0 = __builtin_amdgcn_mfma_f32_16x16x32_bf16(a, wx_[0][kc], acc0, 0, 0, 0);  \
        acc1 = __builtin_amdgcn_mfma_f32_16x16x32_bf16(a, wx_[1][kc], acc1, 0, 0, 0);  \
      }                                                                                \
    }                                                                                  \
    if (wv == 0) { /* wave-parallel poll: lane l watches producer l of group G */      \
      if (t) {                                                                         \
        for (;;) {                                                                     \
          unsigned f = __hip_atomic_load(flags + (G)*64 + lane,                        \
                                         __ATOMIC_RELAXED, __HIP_MEMORY_SCOPE_AGENT); \
          if (__all(f >= (unsigned)t)) break;                                          \
          __builtin_amdgcn_s_sleep(1);                                                 \
        }                                                                              \
      }                                                                                \
      __builtin_amdgcn_fence(__ATOMIC_ACQUIRE, "agent");   /* one buffer_inv */        \
    }                                                                                  \
    __syncthreads();                                                                   \
    { /* stage 16 rows x 2KB into sH: 32 chunks, all in flight */                      \
      const unsigned short* hsrc = hbuf + ((size_t)(t & 1)*BDIM + (R0))*HDIM;          \
      _Pragma("unroll")                                                                \
      for (int it = 0; it < 4; ++it) {                                                 \
        const int ci = wv*4 + it, row = ci >> 1, half = ci & 1;                        \
        gload_lds16(hsrc + (size_t)row*HDIM + half*512 + lane*8,                       \
                    sH + row*HROW + half*512);                                         \
      }                                                                                \
    }                                                                                  \
    __syncthreads();   /* drains global_load_lds vmcnt; sH ready */                    \
    { /* h-path: K-partial gates += h[,K-slice] @ (Wh_hi + Wh_lo)^T */                 \
      const unsigned short* hb = sH + wk*256 + fg*8;                                   \
      _Pragma("unroll")                                                                \
      for (int kc = 0; kc < 8; ++kc) {                                                 \
        frag8 a0 = *(const frag8*)(hb + fr*HROW + kc*32);                              \
        acc0 = __builtin_amdgcn_mfma_f32_16x16x32_bf16(a0, whi_[0][kc], acc0, 0, 0, 0);\
        acc1 = __builtin_amdgcn_mfma_f32_16x16x32_bf16(a0, whi_[1][kc], acc1, 0, 0, 0);\
        acc0 = __builtin_amdgcn_mfma_f32_16x16x32_bf16(a0, wlo_[0][kc], acc0, 0, 0, 0);\
        acc1 = __builtin_amdgcn_mfma_f32_16x16x32_bf16(a0, wlo_[1][kc], acc1, 0, 0, 0);\
      }                                                                                \
    }                                                                                  \
    { /* scatter K-partials (C/D layout: col=lane&15, row=(lane>>4)*4+reg) */          \
      float (*sGw)[SROW] = sG[wk];                                                     \
      _Pragma("unroll")                                                                \
      for (int r = 0; r < 4; ++r) {                                                    \
        sGw[fg*4 + r][(wn*2 + 0)*16 + fr] = acc0[r];                                   \
        sGw[fg*4 + r][(wn*2 + 1)*16 + fr] = acc1[r];                                   \
      }                                                                                \
    }                                                                                  \
    __syncthreads();                                                                   \
    if ((tid >> 8) == (HALF)) { /* K-reduce + nonlinearities + state update */         \
      float gg = bg, gi = bi, gf = bf, go = bo;                                        \
      _Pragma("unroll")                                                                \
      for (int q = 0; q < 4; ++q) {                                                    \
        gg += sG[q][um][uj];                                                           \
        gi += sG[q][um][16 + uj];                                                      \
        gf += sG[q][um][32 + uj];                                                      \
        go += sG[q][um][48 + uj];                                                      \
      }                                                                                \
      CVAR = tanh_f(gg)*sigm(gi) + CVAR*sigm(gf);                                      \
      float h = tanh_f(CVAR)*sigm(go);                                                 \
      unsigned short* hw = hbuf + (size_t)((t + 1) & 1)*BDIM*HDIM;                     \
      st_agent_u16(hw + (size_t)((R0) + um)*HDIM + hc0 + uj, f2bf(h));                 \
      if (t == TSTEPS - 1)                                                             \
        st_agent_f32(hfin + (size_t)((R0) + um)*HDIM + hc0 + uj, h);                   \
    }                                                                                  \
    __syncthreads();   /* drains vmcnt(0): release for the flag store */               \
    if (tid == 0)                                                                      \
      __hip_atomic_store(flags + (G)*64 + nsl, (unsigned)(t + 1),                      \
                         __ATOMIC_RELAXED, __HIP_MEMORY_SCOPE_AGENT);                  \
  }

  for (int t = 0; t < TSTEPS; ++t) {
    PHASE(ga, a0, 0, cA)
    PHASE(gb, b0, 1, cB)
  }
#undef PHASE

  // ---- wait: both row-groups finished all steps (hfin complete for our rows) ----
  if (wv == 0) {
    for (;;) {
      unsigned fa = __hip_atomic_load(flags + ga*64 + lane,
                                      __ATOMIC_RELAXED, __HIP_MEMORY_SCOPE_AGENT);
      unsigned fb = __hip_atomic_load(flags + gb*64 + lane,
                                      __ATOMIC_RELAXED, __HIP_MEMORY_SCOPE_AGENT);
      if (__all(fa >= (unsigned)TSTEPS && fb >= (unsigned)TSTEPS)) break;
      __builtin_amdgcn_s_sleep(1);
    }
    __builtin_amdgcn_fence(__ATOMIC_ACQUIRE, "agent");   // one-shot inv: hfin readable
  }
  __syncthreads();

  // ---- projection: p = h_last @ Wp^T + bp (1 item/thread; halves cover A/B rows) ----
  {
    const int m = ((tid < 256) ? a0 : b0) + um;
    const int n = hc0 + uj;
    const float4* hr = (const float4*)(hfin + (size_t)m*HDIM);
    const float4* wr = (const float4*)(Wp + (size_t)n*HDIM);
    float s = 0.f;
    #pragma unroll 4
    for (int k = 0; k < HDIM/4; ++k) {
      float4 a = hr[k], b = wr[k];
      s += a.x*b.x + a.y*b.y + a.z*b.z + a.w*b.w;
    }
    st_agent_f32(&pbuf[(size_t)m*ODIM + n], s + bp[n]);
  }

  // ---- one-shot full-grid barrier (pbuf complete), then softmax on blocks < 128 ----
  __syncthreads();
  if (tid == 0)
    __hip_atomic_fetch_add(cnt2 + jln*32, 1u, __ATOMIC_RELAXED, __HIP_MEMORY_SCOPE_AGENT);

  if (blockIdx.x >= BDIM) return;

  if (tid == 0) {
    for (;;) {
      unsigned s = 0;
      #pragma unroll
      for (int j = 0; j < 4; ++j)
        s += __hip_atomic_load(cnt2 + j*32, __ATOMIC_RELAXED, __HIP_MEMORY_SCOPE_AGENT);
      if (s >= 256u) break;
      __builtin_amdgcn_s_sleep(1);
    }
    __builtin_amdgcn_fence(__ATOMIC_ACQUIRE, "agent");  // one-shot inv: pbuf readable
  }
  __syncthreads();

  // ---- softmax: one block per batch row (512 thr x float2) ----
  {
    int b = blockIdx.x;
    float* sF = (float*)smem;
    float2 v = ((const float2*)(pbuf + (size_t)b*ODIM))[tid];
    float mx = fmaxf(v.x, v.y);
    #pragma unroll
    for (int off = 32; off > 0; off >>= 1)
      mx = fmaxf(mx, __shfl_xor(mx, off, 64));
    if (lane == 0) sF[wv] = mx;
    __syncthreads();
    mx = sF[0];
    #pragma unroll
    for (int i = 1; i < 8; ++i) mx = fmaxf(mx, sF[i]);
    float e0 = __expf(v.x - mx), e1 = __expf(v.y - mx);
    float s = e0 + e1;
    #pragma unroll
    for (int off = 32; off > 0; off >>= 1)
      s += __shfl_xor(s, off, 64);
    if (lane == 0) sF[8 + wv] = s;
    __syncthreads();
    s = sF[8];
    #pragma unroll
    for (int i = 1; i < 8; ++i) s += sF[8 + i];
    float inv = 1.f / s;
    float2 o; o.x = e0*inv; o.y = e1*inv;
    ((float2*)(out + (size_t)b*ODIM))[tid] = o;
  }
}

// ---------------- host launch ----------------
extern "C" void kernel_launch(void* const* d_in, const int* in_sizes, int n_in,
                              void* d_out, int out_size, void* d_ws, size_t ws_size,
                              hipStream_t stream) {
  (void)in_sizes; (void)n_in; (void)out_size; (void)ws_size;
  const float* x  = (const float*)d_in[0];
  const float* Wx = (const float*)d_in[1];
  const float* bx = (const float*)d_in[2];
  const float* Wh = (const float*)d_in[3];
  const float* Wp = (const float*)d_in[4];
  const float* bp = (const float*)d_in[5];
  float* out = (float*)d_out;
  unsigned char* ws = (unsigned char*)d_ws;

  // zero control block (flags + counters) + h0 double-buffer slot 0
  hipMemsetAsync(ws, 0, WS_HBUF + BDIM*HDIM*2, stream);

  hipLaunchKernelGGL(prep_kernel, dim3(1024), dim3(256), 0, stream, Wh, Wx, x, ws);

  hipFuncSetAttribute(reinterpret_cast<const void*>(&lstm_main),
                      hipFuncAttributeMaxDynamicSharedMemorySize, SMEM_BYTES);
  void* args[5];
  args[0] = (void*)&bx; args[1] = (void*)&Wp; args[2] = (void*)&bp;
  args[3] = (void*)&ws; args[4] = (void*)&out;
  hipLaunchCooperativeKernel(reinterpret_cast<const void*>(&lstm_main),
                             dim3(256), dim3(512), args, SMEM_BYTES, stream);
}